// Round 6
// baseline (360.348 us; speedup 1.0000x reference)
//
#include <hip/hip_runtime.h>
#include <stdint.h>

#define BATCH 16384
#define DDIM  3072
#define NK    300
#define NKP   320
#define NCLS  10

#define BM 64
#define BN 320
#define BK 64
#define KT (DDIM / BK)   // 48

typedef __bf16 bf16x8 __attribute__((ext_vector_type(8)));
typedef float  f32x16 __attribute__((ext_vector_type(16)));

typedef __attribute__((address_space(1))) const void gvoid_as1;
typedef __attribute__((address_space(3))) void lvoid_as3;

__device__ __forceinline__ unsigned f2bf(float f) {
  unsigned u = __float_as_uint(f);
  u += 0x7FFFu + ((u >> 16) & 1u);   // RNE
  return u >> 16;
}
__device__ __forceinline__ uint4 pack8bf(float4 a, float4 b) {
  uint4 p;
  p.x = f2bf(a.x) | (f2bf(a.y) << 16);
  p.y = f2bf(a.z) | (f2bf(a.w) << 16);
  p.z = f2bf(b.x) | (f2bf(b.y) << 16);
  p.w = f2bf(b.z) | (f2bf(b.w) << 16);
  return p;
}

// ---------------------------------------------------------------- prep_w ----
// w5 (300x3072 f32) -> wn bf16 (320x3072, rows 300..319 zero), rw[k]=1/(|w|+eps)
__global__ __launch_bounds__(256) void prep_w_kernel(
    const float* __restrict__ w5, unsigned short* __restrict__ wn,
    float* __restrict__ rw, float* __restrict__ gsum, float* __restrict__ gsq) {
  const int r = blockIdx.x;
  const int t = threadIdx.x;
  if (r == 0) {  // zero stat accumulators (gemm runs after this kernel)
    for (int i = t; i < NKP; i += 256) { gsum[i] = 0.f; gsq[i] = 0.f; }
  }
  unsigned long long* dst = (unsigned long long*)(wn + (size_t)r * DDIM);
  if (r < NK) {
    const float4* src = (const float4*)(w5 + (size_t)r * DDIM);
    float ss = 0.f;
#pragma unroll
    for (int i = 0; i < 3; ++i) {
      float4 v = src[t + i * 256];
      ss += v.x * v.x + v.y * v.y + v.z * v.z + v.w * v.w;
      unsigned lo = f2bf(v.x) | (f2bf(v.y) << 16);
      unsigned hi = f2bf(v.z) | (f2bf(v.w) << 16);
      dst[t + i * 256] = (unsigned long long)lo | ((unsigned long long)hi << 32);
    }
#pragma unroll
    for (int m = 1; m <= 32; m <<= 1) ss += __shfl_xor(ss, m, 64);
    __shared__ float red[4];
    if ((t & 63) == 0) red[t >> 6] = ss;
    __syncthreads();
    if (t == 0) {
      float tot = red[0] + red[1] + red[2] + red[3];
      rw[r] = 1.f / (sqrtf(tot) + 1e-12f);
    }
  } else {
#pragma unroll
    for (int i = 0; i < 3; ++i) dst[t + i * 256] = 0ull;
    if (t == 0) rw[r] = 0.f;
  }
}

// ------------------------------------------------------------------ gemm ----
// fc5[m][n] = relu( (x[m]. wn[n]) * rx[m] * rw[n] ), plus per-n sum/sumsq atomics.
// 320 threads = 5 waves. Each wave owns a 64x64 output tile (2x2 frags of
// 32x32x16 MFMA) at cols [w*64, w*64+64). BN=320 => x fetched once from HBM.
__global__ __launch_bounds__(320, 2) void gemm_kernel(
    const float* __restrict__ x, const unsigned short* __restrict__ wn,
    const float* __restrict__ rw, float* __restrict__ fc5,
    float* __restrict__ gsum, float* __restrict__ gsq) {
  __shared__ alignas(16) unsigned short xs[BM * BK];   // 8 KB, XOR-swizzled
  __shared__ alignas(16) unsigned short wt[BN * BK];   // 40 KB, XOR-swizzled
  __shared__ float rxs[BM];

  const int tid  = threadIdx.x;
  const int lane = tid & 63;
  const int w    = tid >> 6;          // wave 0..4
  const int m0   = (int)blockIdx.x * BM;

  // ---- x staging map (threads 0..255): row = t>>2, 16-float segment (t&3) ----
  const int srow = tid >> 2;
  const int sseg = tid & 3;
  const float* xsrc = x + (size_t)(m0 + srow) * DDIM + sseg * 16;
  const int wb0 = srow * 128 + ((((sseg << 1) | 0) ^ (srow & 7)) << 4);
  const int wb1 = srow * 128 + ((((sseg << 1) | 1) ^ (srow & 7)) << 4);

  // ---- w staging map: 8 x 1KB chunks per wave (chunk i -> rows 8i..8i+7) ----
  const int wrow_l = lane >> 3;                 // 0..7 within chunk
  const int wchk_l = (lane & 7) ^ wrow_l;       // inverse-swizzled source chunk
  const unsigned short* wsrc_base = wn + (size_t)wrow_l * DDIM + wchk_l * 8;

  // ---- fragment addresses ----
  const int r31   = lane & 31;
  const int khalf = lane >> 5;
  const int rb0 = w * 64 + r31;
  const int rb1 = rb0 + 32;
  const char* aA0 = (const char*)xs + (size_t)r31 * 128;
  const char* aA1 = (const char*)xs + (size_t)(r31 + 32) * 128;
  const char* aB0 = (const char*)wt + (size_t)rb0 * 128;
  const char* aB1 = (const char*)wt + (size_t)rb1 * 128;
  const int swzA = r31 & 7;      // same for r31+32
  const int swzB0 = rb0 & 7, swzB1 = rb1 & 7;

  f32x16 acc00 = {}, acc01 = {}, acc10 = {}, acc11 = {};
  float ss = 0.f;

  float4 v0, v1, v2, v3;
  if (tid < 256) {
    const float4* p = (const float4*)xsrc;
    v0 = p[0]; v1 = p[1]; v2 = p[2]; v3 = p[3];
  }

  for (int kt = 0; kt < KT; ++kt) {
    // ---- stage phase ----
    if (tid < 256) {
      ss += v0.x*v0.x + v0.y*v0.y + v0.z*v0.z + v0.w*v0.w
          + v1.x*v1.x + v1.y*v1.y + v1.z*v1.z + v1.w*v1.w
          + v2.x*v2.x + v2.y*v2.y + v2.z*v2.z + v2.w*v2.w
          + v3.x*v3.x + v3.y*v3.y + v3.z*v3.z + v3.w*v3.w;
      *(uint4*)((char*)xs + wb0) = pack8bf(v0, v1);
      *(uint4*)((char*)xs + wb1) = pack8bf(v2, v3);
    }
#pragma unroll
    for (int j = 0; j < 8; ++j) {
      const int i = w * 8 + j;                          // chunk 0..39
      const unsigned short* src = wsrc_base + (size_t)(8 * i) * DDIM + kt * BK;
      __builtin_amdgcn_global_load_lds((gvoid_as1*)src,
                                       (lvoid_as3*)((char*)wt + i * 1024), 16, 0, 0);
    }
    __syncthreads();                                    // drains vmcnt/lgkm
    // prefetch next x tile during compute (HBM latency hides under MFMA)
    if (kt + 1 < KT && tid < 256) {
      const float4* p = (const float4*)(xsrc + (size_t)(kt + 1) * BK);
      v0 = p[0]; v1 = p[1]; v2 = p[2]; v3 = p[3];
    }
    // ---- compute phase: 4 k-steps x 4 MFMA ----
#pragma unroll
    for (int ks = 0; ks < 4; ++ks) {
      const int c16 = ks * 2 + khalf;
      bf16x8 a0 = *(const bf16x8*)(aA0 + ((c16 ^ swzA) << 4));
      bf16x8 a1 = *(const bf16x8*)(aA1 + ((c16 ^ swzA) << 4));
      bf16x8 b0 = *(const bf16x8*)(aB0 + ((c16 ^ swzB0) << 4));
      bf16x8 b1 = *(const bf16x8*)(aB1 + ((c16 ^ swzB1) << 4));
      acc00 = __builtin_amdgcn_mfma_f32_32x32x16_bf16(a0, b0, acc00, 0, 0, 0);
      acc01 = __builtin_amdgcn_mfma_f32_32x32x16_bf16(a0, b1, acc01, 0, 0, 0);
      acc10 = __builtin_amdgcn_mfma_f32_32x32x16_bf16(a1, b0, acc10, 0, 0, 0);
      acc11 = __builtin_amdgcn_mfma_f32_32x32x16_bf16(a1, b1, acc11, 0, 0, 0);
    }
    if (kt + 1 < KT) __syncthreads();                   // LDS reuse guard
  }

  // ---- inverse x-row norms (4 threads per row, consecutive lanes) ----
  ss += __shfl_xor(ss, 1, 64);
  ss += __shfl_xor(ss, 2, 64);
  if (tid < 256 && sseg == 0) rxs[srow] = 1.f / (sqrtf(ss) + 1e-12f);
  __syncthreads();

  // ---- epilogue: scale, relu, store fc5, per-channel stats ----
  const int kh4 = khalf * 4;
  const int ng0 = w * 64 + r31;        // < 288 always
  const int ng1 = ng0 + 32;            // up to 319
  const float rwv0 = rw[ng0];
  const float rwv1 = rw[ng1];
  float s0 = 0.f, q0 = 0.f, s1 = 0.f, q1 = 0.f;

#define EPI(ACC, MI, NG, RWV, SV, QV)                                         \
  _Pragma("unroll")                                                           \
  for (int r = 0; r < 16; ++r) {                                              \
    const int row = MI * 32 + (r & 3) + 8 * (r >> 2) + kh4;                   \
    float v = ACC[r] * rxs[row] * RWV;                                        \
    v = fmaxf(v, 0.f);                                                        \
    if (NG < NK) fc5[(size_t)(m0 + row) * NK + NG] = v;                       \
    SV += v; QV += v * v;                                                     \
  }
  EPI(acc00, 0, ng0, rwv0, s0, q0)
  EPI(acc01, 0, ng1, rwv1, s1, q1)
  EPI(acc10, 1, ng0, rwv0, s0, q0)
  EPI(acc11, 1, ng1, rwv1, s1, q1)
#undef EPI

  s0 += __shfl_xor(s0, 32, 64); q0 += __shfl_xor(q0, 32, 64);
  s1 += __shfl_xor(s1, 32, 64); q1 += __shfl_xor(q1, 32, 64);
  if (lane < 32) {
    atomicAdd(&gsum[ng0], s0); atomicAdd(&gsq[ng0], q0);
    if (ng1 < NK) { atomicAdd(&gsum[ng1], s1); atomicAdd(&gsq[ng1], q1); }
  }
}

// ---------------------------------------------------------------- bn+fc6 ----
// Finalizes stats per block (redundant, cheap), applies BN, 300->10 readout.
__global__ __launch_bounds__(256) void bn_fc6_kernel(
    const float* __restrict__ fc5, const float* __restrict__ w6,
    const float* __restrict__ gamma, const float* __restrict__ beta,
    const float* __restrict__ gsum, const float* __restrict__ gsq,
    float* __restrict__ bn5, float* __restrict__ fc6) {
  __shared__ float w6s[NCLS * NK];
  __shared__ float scs[NK], shs[NK];
  const int t = threadIdx.x;
  for (int i = t; i < NCLS * NK; i += 256) w6s[i] = w6[i];
  for (int i = t; i < NK; i += 256) {
    const float invB = 1.f / (float)BATCH;
    float mean = gsum[i] * invB;
    float var  = gsq[i] * invB - mean * mean;
    var = fmaxf(var, 0.f);
    float sc = gamma[i] * rsqrtf(var + 1e-5f);
    scs[i] = sc;
    shs[i] = beta[i] - mean * sc;
  }
  __syncthreads();
  const int wv = t >> 6, l = t & 63;
  const int r = (int)blockIdx.x * 4 + wv;
  const float* frow = fc5 + (size_t)r * NK;
  float* brow = bn5 + (size_t)r * NK;
  float accv[NCLS];
#pragma unroll
  for (int o = 0; o < NCLS; ++o) accv[o] = 0.f;
#pragma unroll
  for (int i = 0; i < 5; ++i) {
    const int k = i * 64 + l;
    if (k < NK) {
      float b = frow[k] * scs[k] + shs[k];
      brow[k] = b;
#pragma unroll
      for (int o = 0; o < NCLS; ++o) accv[o] += b * w6s[o * NK + k];
    }
  }
#pragma unroll
  for (int o = 0; o < NCLS; ++o) {
    float v = accv[o];
#pragma unroll
    for (int m = 1; m <= 32; m <<= 1) v += __shfl_xor(v, m, 64);
    if (l == 0) fc6[(size_t)r * NCLS + o] = v;
  }
}

// ---------------------------------------------------------------- launch ----
extern "C" void kernel_launch(void* const* d_in, const int* in_sizes, int n_in,
                              void* d_out, int out_size, void* d_ws, size_t ws_size,
                              hipStream_t stream) {
  const float* x     = (const float*)d_in[0];
  const float* w5    = (const float*)d_in[1];
  const float* gamma = (const float*)d_in[2];
  const float* beta  = (const float*)d_in[3];
  const float* w6    = (const float*)d_in[4];

  float* fc5 = (float*)d_out;
  float* bn5 = fc5 + (size_t)BATCH * NK;
  float* fc6 = bn5 + (size_t)BATCH * NK;

  char* ws = (char*)d_ws;
  unsigned short* wn = (unsigned short*)ws;                 // 320*3072*2 B
  float* rw   = (float*)(ws + (size_t)NKP * DDIM * 2);
  float* gsum = rw + NKP;
  float* gsq  = gsum + NKP;

  hipLaunchKernelGGL(prep_w_kernel, dim3(NKP), dim3(256), 0, stream,
                     w5, wn, rw, gsum, gsq);
  hipLaunchKernelGGL(gemm_kernel, dim3(BATCH / BM), dim3(320), 0, stream,
                     x, wn, rw, fc5, gsum, gsq);
  hipLaunchKernelGGL(bn_fc6_kernel, dim3(BATCH / 4), dim3(256), 0, stream,
                     fc5, w6, gamma, beta, gsum, gsq, bn5, fc6);
}